// Round 16
// baseline (346.163 us; speedup 1.0000x reference)
//
#include <hip/hip_runtime.h>
#include <math.h>

#define T 8
#define N 5000
#define E 160000
#define EN (E + N)
#define IN_DIM 64
#define HID 128
#define H 8
#define D 16
#define NC 2
#define MT 32            // rows per tiled-GEMM block
#define NBF 4            // nodes per k_fuse block
#define NRR 8            // dst ranges for k_scatter
#define NCHK 32          // edge chunks per t for k_scatter
#define NHCH 32          // edge chunks per t for k_hist
#define RSZ ((N + NRR - 1) / NRR)      // 625
#define CSZ ((EN + NCHK - 1) / NCHK)   // 5157

#define NB_HIST (T * NHCH)             // 256 hist-role blocks
#define NB_TR   256                    // transpose-role blocks
#define NB_PG   (T * N / MT)           // 1250 GEMM-role blocks

__device__ __forceinline__ float leaky(float e) { return (e >= 0.0f) ? e : 0.2f * e; }

// k_front: three independent roles fused into one dispatch so they overlap:
//   blocks [0, NB_HIST)            : LDS-privatized degree histogram
//   blocks [NB_HIST, +NB_TR)       : W_qkv / W_o transposes
//   blocks [NB_HIST+NB_TR, +NB_PG) : fused h=relu(x@Wp+bp); xh=h@Wg; a_s/a_d
// cursor must be zeroed by hipMemsetAsync BEFORE this kernel.
__global__ __launch_bounds__(256) void k_front(
        // pg role
        const float* __restrict__ x,
        const float* __restrict__ Wp,
        const float* __restrict__ bp,
        const float* __restrict__ Wg,
        const float* __restrict__ asrc,
        const float* __restrict__ adst,
        float* __restrict__ xh,
        float* __restrict__ a_s,
        float* __restrict__ a_d,
        // tr role
        const float* __restrict__ W_qkv,
        const float* __restrict__ W_o,
        float* __restrict__ WTq,
        float* __restrict__ WoT,
        // hist role
        const int* __restrict__ ei,
        int* __restrict__ cursor) {
    __shared__ float smem[6272];      // 25,088 B: pg 24,704 / hist 20,000
    int bid = blockIdx.x;
    int tid = threadIdx.x;

    if (bid < NB_HIST) {
        // ---------------- histogram role ----------------
        int* hist = (int*)smem;       // N ints = 20,000 B
        int t = bid >> 5;
        int chunk = bid & 31;

        for (int i = tid; i < N; i += 256) hist[i] = 0;
        __syncthreads();

        const int CS = (EN + NHCH - 1) / NHCH;   // 5157
        int i0 = chunk * CS;
        int i1 = (i0 + CS < EN) ? i0 + CS : EN;
        const int* drow = ei + (size_t)(2 * t + 1) * E;
        for (int i = i0 + tid; i < i1; i += 256) {
            int d = (i < E) ? drow[i] : (i - E);
            atomicAdd(&hist[d], 1);
        }
        __syncthreads();

        int* cur = cursor + t * N;
        for (int i = tid; i < N; i += 256) {
            int c = hist[i];
            if (c) atomicAdd(&cur[i], c);
        }
        return;
    }

    if (bid < NB_HIST + NB_TR) {
        // ---------------- transpose role ----------------
        int idx = (bid - NB_HIST) * 256 + tid;
        if (idx < 384 * 128) {
            int j = idx >> 7, c = idx & 127;
            WTq[c * 384 + j] = W_qkv[idx];
        } else if (idx < 384 * 128 + 128 * 128) {
            int r = idx - 384 * 128;
            int j = r >> 7, k = r & 127;
            WoT[k * 128 + j] = W_o[r];
        }
        return;
    }

    // ---------------- pg (GEMM) role ----------------
    float (*xt)[IN_DIM] = (float (*)[IN_DIM])smem;
    float (*ht)[HID + 1] = (float (*)[HID + 1])(smem + MT * IN_DIM);
    int row0 = (bid - NB_HIST - NB_TR) * MT;

    for (int idx = tid; idx < MT * IN_DIM; idx += 256) {
        int r = idx >> 6, k = idx & 63;
        xt[r][k] = x[(size_t)(row0 + r) * IN_DIM + k];
    }
    __syncthreads();

    int cg = tid & 31;
    int rg = tid >> 5;
    int c0 = cg * 4, r0 = rg * 4;

    {
        float4 b4 = *(const float4*)(bp + c0);
        float a00=b4.x,a01=b4.y,a02=b4.z,a03=b4.w;
        float a10=b4.x,a11=b4.y,a12=b4.z,a13=b4.w;
        float a20=b4.x,a21=b4.y,a22=b4.z,a23=b4.w;
        float a30=b4.x,a31=b4.y,a32=b4.z,a33=b4.w;
        for (int k = 0; k < IN_DIM; ++k) {
            float4 w = *(const float4*)(Wp + (size_t)k * HID + c0);
            float x0 = xt[r0 + 0][k], x1 = xt[r0 + 1][k];
            float x2 = xt[r0 + 2][k], x3 = xt[r0 + 3][k];
            a00 += x0*w.x; a01 += x0*w.y; a02 += x0*w.z; a03 += x0*w.w;
            a10 += x1*w.x; a11 += x1*w.y; a12 += x1*w.z; a13 += x1*w.w;
            a20 += x2*w.x; a21 += x2*w.y; a22 += x2*w.z; a23 += x2*w.w;
            a30 += x3*w.x; a31 += x3*w.y; a32 += x3*w.z; a33 += x3*w.w;
        }
        ht[r0+0][c0+0]=fmaxf(a00,0.f); ht[r0+0][c0+1]=fmaxf(a01,0.f);
        ht[r0+0][c0+2]=fmaxf(a02,0.f); ht[r0+0][c0+3]=fmaxf(a03,0.f);
        ht[r0+1][c0+0]=fmaxf(a10,0.f); ht[r0+1][c0+1]=fmaxf(a11,0.f);
        ht[r0+1][c0+2]=fmaxf(a12,0.f); ht[r0+1][c0+3]=fmaxf(a13,0.f);
        ht[r0+2][c0+0]=fmaxf(a20,0.f); ht[r0+2][c0+1]=fmaxf(a21,0.f);
        ht[r0+2][c0+2]=fmaxf(a22,0.f); ht[r0+2][c0+3]=fmaxf(a23,0.f);
        ht[r0+3][c0+0]=fmaxf(a30,0.f); ht[r0+3][c0+1]=fmaxf(a31,0.f);
        ht[r0+3][c0+2]=fmaxf(a32,0.f); ht[r0+3][c0+3]=fmaxf(a33,0.f);
    }
    __syncthreads();

    float a00=0,a01=0,a02=0,a03=0, a10=0,a11=0,a12=0,a13=0;
    float a20=0,a21=0,a22=0,a23=0, a30=0,a31=0,a32=0,a33=0;
    for (int k = 0; k < HID; ++k) {
        float4 w = *(const float4*)(Wg + (size_t)k * HID + c0);
        float h0 = ht[r0 + 0][k], h1 = ht[r0 + 1][k];
        float h2 = ht[r0 + 2][k], h3 = ht[r0 + 3][k];
        a00 += h0*w.x; a01 += h0*w.y; a02 += h0*w.z; a03 += h0*w.w;
        a10 += h1*w.x; a11 += h1*w.y; a12 += h1*w.z; a13 += h1*w.w;
        a20 += h2*w.x; a21 += h2*w.y; a22 += h2*w.z; a23 += h2*w.w;
        a30 += h3*w.x; a31 += h3*w.y; a32 += h3*w.z; a33 += h3*w.w;
    }
    {
        float4 v;
        v.x=a00; v.y=a01; v.z=a02; v.w=a03;
        *(float4*)(xh + (size_t)(row0 + r0 + 0) * HID + c0) = v;
        v.x=a10; v.y=a11; v.z=a12; v.w=a13;
        *(float4*)(xh + (size_t)(row0 + r0 + 1) * HID + c0) = v;
        v.x=a20; v.y=a21; v.z=a22; v.w=a23;
        *(float4*)(xh + (size_t)(row0 + r0 + 2) * HID + c0) = v;
        v.x=a30; v.y=a31; v.z=a32; v.w=a33;
        *(float4*)(xh + (size_t)(row0 + r0 + 3) * HID + c0) = v;
    }
    __syncthreads();
    ht[r0+0][c0+0]=a00; ht[r0+0][c0+1]=a01; ht[r0+0][c0+2]=a02; ht[r0+0][c0+3]=a03;
    ht[r0+1][c0+0]=a10; ht[r0+1][c0+1]=a11; ht[r0+1][c0+2]=a12; ht[r0+1][c0+3]=a13;
    ht[r0+2][c0+0]=a20; ht[r0+2][c0+1]=a21; ht[r0+2][c0+2]=a22; ht[r0+2][c0+3]=a23;
    ht[r0+3][c0+0]=a30; ht[r0+3][c0+1]=a31; ht[r0+3][c0+2]=a32; ht[r0+3][c0+3]=a33;
    __syncthreads();

    {
        int r = tid >> 3, hh = tid & 7;
        float s1 = 0.0f, s2 = 0.0f;
        #pragma unroll
        for (int d = 0; d < D; ++d) {
            float v = ht[r][hh * D + d];
            s1 += v * asrc[hh * D + d];
            s2 += v * adst[hh * D + d];
        }
        a_s[(size_t)(row0 + r) * H + hh] = s1;
        a_d[(size_t)(row0 + r) * H + hh] = s2;
    }
}

__global__ void k_scan(int* __restrict__ cursor, int* __restrict__ offs) {
    __shared__ int part[256];
    int t = blockIdx.x;
    int tid = threadIdx.x;
    const int CH = 20;
    int begin = tid * CH;
    int sum = 0;
    for (int k = 0; k < CH; ++k) {
        int i = begin + k;
        if (i < N) sum += cursor[t * N + i];
    }
    part[tid] = sum;
    __syncthreads();
    if (tid == 0) {
        int run = 0;
        for (int i = 0; i < 256; ++i) { int v = part[i]; part[i] = run; run += v; }
        offs[t * (N + 1) + N] = run;
    }
    __syncthreads();
    int run = part[tid];
    for (int k = 0; k < CH; ++k) {
        int i = begin + k;
        if (i < N) {
            int cnt = cursor[t * N + i];
            offs[t * (N + 1) + i] = run;
            cursor[t * N + i] = run;
            run += cnt;
        }
    }
}

// range-localized scatter, CSR packed as ushort (src < N < 65536): halves the
// random-write line traffic and k_aggc's edge-list fetch. Block = (t, dst
// range r, edge chunk c); index swizzle pins each (t,r)'s chunks to one XCD.
__global__ __launch_bounds__(256) void k_scatter(const int* __restrict__ ei,
                                                 int* __restrict__ cursor,
                                                 unsigned short* __restrict__ csr_src) {
    int idx = blockIdx.x;
    int g = idx & 63;            // (t, r)
    int c = idx >> 6;            // chunk
    int t = g >> 3;
    int r = g & 7;
    int lo = r * RSZ;
    int hi = (lo + RSZ < N) ? lo + RSZ : N;
    int i0 = c * CSZ;
    int i1 = (i0 + CSZ < EN) ? i0 + CSZ : EN;

    const int* srow = ei + (size_t)(2 * t) * E;
    const int* drow = srow + E;
    int* cur = cursor + t * N;
    unsigned short* csb = csr_src + (size_t)t * EN;

    for (int i = i0 + threadIdx.x; i < i1; i += 256) {
        int s, d;
        if (i < E) { d = drow[i]; s = srow[i]; }
        else       { s = d = i - E; }
        if (d >= lo && d < hi) {
            int pos = atomicAdd(&cur[d], 1);
            csb[pos] = (unsigned short)s;
        }
    }
}

// GAT aggregation + fused LN1, one block per (dst,t), atomic-free and
// BARRIER-FREE inner loop. Single-pass softmax. Node-major nrm. ushort CSR.
__global__ __launch_bounds__(128) void k_aggc(
        const int* __restrict__ offs, const unsigned short* __restrict__ csr_src,
        const float* __restrict__ a_s, const float* __restrict__ a_d,
        const float* __restrict__ xh, const float* __restrict__ b_gat,
        const float* __restrict__ g1, const float* __restrict__ be1,
        float* __restrict__ nrm, float* __restrict__ xlast_g) {
    int b = blockIdx.x;
    int t = b & 7;            // T == 8
    int dst = b >> 3;
    int tid = threadIdx.x;

    int o0 = offs[t * (N + 1) + dst];
    int o1 = offs[t * (N + 1) + dst + 1];
    int deg = o1 - o0;
    const unsigned short* esrc = csr_src + (size_t)t * EN + o0;
    const float* as_b = a_s + (size_t)t * N * H;
    const float* ad_b = a_d + (size_t)t * N * H;
    const float* xh_b = xh + (size_t)t * N * HID;

    __shared__ float ws_s[2][H];     // per-wave wsum partials
    __shared__ float pacc[2][HID];   // per-wave acc partials
    __shared__ float red[128];

    int el = tid >> 5;               // edge-lane: edges ej % 4 == el
    int cg = tid & 31;               // col group (cols 4cg..4cg+3)
    int hg = cg >> 2;                // head of these cols
    float adh = ad_b[dst * H + hg];

    float4 acc = {0.0f, 0.0f, 0.0f, 0.0f};
    float wpart = 0.0f;

    #pragma unroll 4
    for (int ej = el; ej < deg; ej += 4) {
        int src = esrc[ej];
        float w = expf(leaky(as_b[src * H + hg] + adh));
        wpart += w;
        float4 v = *(const float4*)(xh_b + (size_t)src * HID + (cg << 2));
        acc.x += w * v.x; acc.y += w * v.y;
        acc.z += w * v.z; acc.w += w * v.w;
    }

    wpart += __shfl_xor(wpart, 32);
    acc.x += __shfl_xor(acc.x, 32);
    acc.y += __shfl_xor(acc.y, 32);
    acc.z += __shfl_xor(acc.z, 32);
    acc.w += __shfl_xor(acc.w, 32);
    if (!(tid & 32)) {
        if ((cg & 3) == 0) ws_s[tid >> 6][hg] = wpart;
        *(float4*)&pacc[tid >> 6][cg << 2] = acc;
    }
    __syncthreads();

    float wsum = ws_s[0][tid >> 4] + ws_s[1][tid >> 4];
    float val = (pacc[0][tid] + pacc[1][tid]) / (wsum + 1e-16f);

    // ---- fused LN1 over this (t,dst) row ----
    float v = val + b_gat[tid];
    red[tid] = v;
    __syncthreads();
    if (tid < 64) {
        float s = red[tid] + red[tid + 64];
        #pragma unroll
        for (int m = 1; m < 64; m <<= 1) s += __shfl_xor(s, m);
        if (tid == 0) red[0] = s;
    }
    __syncthreads();
    float mu = red[0] * (1.0f / HID);
    __syncthreads();
    float dv = v - mu;
    red[tid] = dv * dv;
    __syncthreads();
    if (tid < 64) {
        float s = red[tid] + red[tid + 64];
        #pragma unroll
        for (int m = 1; m < 64; m <<= 1) s += __shfl_xor(s, m);
        if (tid == 0) red[0] = s;
    }
    __syncthreads();
    float rstd = rsqrtf(red[0] * (1.0f / HID) + 1e-5f);

    nrm[(size_t)(dst * T + t) * HID + tid] = dv * rstd * g1[tid] + be1[tid];
    if (t == T - 1) xlast_g[(size_t)dst * HID + tid] = v;
}

// fused qkv GEMM + attention + W_o + LN2 + epilogue for NBF=4 nodes/block.
// Weight chunks staged via async global_load_lds into a DOUBLE-BUFFERED ws.
__global__ __launch_bounds__(256) void k_fuse(
        const float* __restrict__ nrm,      // [N*T][HID] node-major
        const float* __restrict__ WTq,      // [128][384]
        const float* __restrict__ b_qkv,
        const float* __restrict__ xlast_g,
        const float* __restrict__ WoT,
        const float* __restrict__ b_o,
        const float* __restrict__ g2, const float* __restrict__ be2,
        const float* __restrict__ noise, float* __restrict__ out) {
    __shared__ float at[NBF * T][HID];       // 16 KB; ta_s aliases after GEMM
    __shared__ float ql[NBF][HID];           // 2 KB
    __shared__ float ws[2][8][384];          // 24 KB double-buffered stage
    float* ta_s = &at[0][0];                 // [NBF][HID] = 512 floats (alias)

    int n0 = blockIdx.x * NBF;
    int tid = threadIdx.x;
    int cg = tid & 31, rg = tid >> 5;
    int c0 = cg * 4, r0 = rg * 4;
    int u = rg >> 1;                         // node of this thread's 4 rows
    int lane = tid & 63, wv = tid >> 6;

    auto stage = [&](int kc, int buf) {
        const float* g = WTq + (size_t)kc * 3072 + wv * 768 + (lane << 2);
        float* l = &ws[buf][0][0] + wv * 768;
        #pragma unroll
        for (int j = 0; j < 3; ++j) {
            __builtin_amdgcn_global_load_lds(
                (const __attribute__((address_space(1))) void*)(g + j * 256),
                (__attribute__((address_space(3))) void*)(l + j * 256),
                16, 0, 0);
        }
    };

    // load 32 rows of nrm (coalesced float4)
    {
        const float* srcp = nrm + (size_t)n0 * T * HID;
        for (int idx = tid; idx < NBF * T * 32; idx += 256) {
            int r = idx >> 5, c4 = (idx & 31) << 2;
            *(float4*)&at[r][c4] = *(const float4*)(srcp + (size_t)r * HID + c4);
        }
    }
    stage(0, 0);                             // prologue: chunk 0 in flight

    // accumulators (bias-initialized)
    float ka[4][4], va[4][4], qa[4];
    {
        float4 bk = *(const float4*)(b_qkv + 128 + c0);
        float4 bv = *(const float4*)(b_qkv + 256 + c0);
        #pragma unroll
        for (int i = 0; i < 4; ++i) {
            ka[i][0] = bk.x; ka[i][1] = bk.y; ka[i][2] = bk.z; ka[i][3] = bk.w;
            va[i][0] = bv.x; va[i][1] = bv.y; va[i][2] = bv.z; va[i][3] = bv.w;
        }
        if (rg < 4) {
            float4 bq = *(const float4*)(b_qkv + c0);
            qa[0] = bq.x; qa[1] = bq.y; qa[2] = bq.z; qa[3] = bq.w;
        } else {
            qa[0] = qa[1] = qa[2] = qa[3] = 0.0f;
        }
    }
    __syncthreads();                         // at ready + ws[0] drained

    const float* atq = at[(rg & 3) * T + (T - 1)];  // q source row (waves 0-1)

    int cur = 0;
    for (int kc = 0; kc < 16; ++kc) {
        if (kc < 15) stage(kc + 1, cur ^ 1); // async, hidden under compute

        #pragma unroll
        for (int kk = 0; kk < 8; kk += 4) {
            int k = kc * 8 + kk;
            float4 e0 = *(const float4*)&at[r0 + 0][k];
            float4 e1 = *(const float4*)&at[r0 + 1][k];
            float4 e2 = *(const float4*)&at[r0 + 2][k];
            float4 e3 = *(const float4*)&at[r0 + 3][k];
            float e0a[4] = {e0.x, e0.y, e0.z, e0.w};
            float e1a[4] = {e1.x, e1.y, e1.z, e1.w};
            float e2a[4] = {e2.x, e2.y, e2.z, e2.w};
            float e3a[4] = {e3.x, e3.y, e3.z, e3.w};
            float eqa[4] = {0.f, 0.f, 0.f, 0.f};
            if (rg < 4) {
                float4 eq = *(const float4*)&atq[k];
                eqa[0] = eq.x; eqa[1] = eq.y; eqa[2] = eq.z; eqa[3] = eq.w;
            }
            #pragma unroll
            for (int j = 0; j < 4; ++j) {
                float4 wk = *(const float4*)&ws[cur][kk + j][128 + c0];
                float4 wv4 = *(const float4*)&ws[cur][kk + j][256 + c0];
                float x0 = e0a[j], x1 = e1a[j], x2 = e2a[j], x3 = e3a[j];
                ka[0][0] += x0*wk.x; ka[0][1] += x0*wk.y; ka[0][2] += x0*wk.z; ka[0][3] += x0*wk.w;
                ka[1][0] += x1*wk.x; ka[1][1] += x1*wk.y; ka[1][2] += x1*wk.z; ka[1][3] += x1*wk.w;
                ka[2][0] += x2*wk.x; ka[2][1] += x2*wk.y; ka[2][2] += x2*wk.z; ka[2][3] += x2*wk.w;
                ka[3][0] += x3*wk.x; ka[3][1] += x3*wk.y; ka[3][2] += x3*wk.z; ka[3][3] += x3*wk.w;
                va[0][0] += x0*wv4.x; va[0][1] += x0*wv4.y; va[0][2] += x0*wv4.z; va[0][3] += x0*wv4.w;
                va[1][0] += x1*wv4.x; va[1][1] += x1*wv4.y; va[1][2] += x1*wv4.z; va[1][3] += x1*wv4.w;
                va[2][0] += x2*wv4.x; va[2][1] += x2*wv4.y; va[2][2] += x2*wv4.z; va[2][3] += x2*wv4.w;
                va[3][0] += x3*wv4.x; va[3][1] += x3*wv4.y; va[3][2] += x3*wv4.z; va[3][3] += x3*wv4.w;
                if (rg < 4) {
                    float4 wq = *(const float4*)&ws[cur][kk + j][c0];
                    float xq = eqa[j];
                    qa[0] += xq*wq.x; qa[1] += xq*wq.y; qa[2] += xq*wq.z; qa[3] += xq*wq.w;
                }
            }
        }
        __syncthreads();   // retires ws[cur] reads + drains kc+1's async loads
        cur ^= 1;
    }

    // q to LDS (waves 0-1)
    if (rg < 4) {
        float4 q4; q4.x = qa[0]; q4.y = qa[1]; q4.z = qa[2]; q4.w = qa[3];
        *(float4*)&ql[rg][c0] = q4;
    }
    __syncthreads();

    // scores in registers; quad shfl completes dot; partner shfl(32) for
    // softmax + PV.
    float p0, p1, p2, p3;
    {
        float4 q4 = *(const float4*)&ql[u][c0];
        float ps[4];
        #pragma unroll
        for (int i = 0; i < 4; ++i) {
            float s = q4.x * ka[i][0] + q4.y * ka[i][1]
                    + q4.z * ka[i][2] + q4.w * ka[i][3];
            s += __shfl_xor(s, 1);
            s += __shfl_xor(s, 2);
            ps[i] = s * 0.25f;          // 1/sqrt(D)
        }
        float mx = fmaxf(fmaxf(ps[0], ps[1]), fmaxf(ps[2], ps[3]));
        mx = fmaxf(mx, __shfl_xor(mx, 32));
        float e0 = expf(ps[0] - mx), e1 = expf(ps[1] - mx);
        float e2 = expf(ps[2] - mx), e3 = expf(ps[3] - mx);
        float ssum = e0 + e1 + e2 + e3;
        ssum += __shfl_xor(ssum, 32);
        float inv = 1.0f / ssum;
        p0 = (e0 * va[0][0] + e1 * va[1][0] + e2 * va[2][0] + e3 * va[3][0]) * inv;
        p1 = (e0 * va[0][1] + e1 * va[1][1] + e2 * va[2][1] + e3 * va[3][1]) * inv;
        p2 = (e0 * va[0][2] + e1 * va[1][2] + e2 * va[2][2] + e3 * va[3][2]) * inv;
        p3 = (e0 * va[0][3] + e1 * va[1][3] + e2 * va[2][3] + e3 * va[3][3]) * inv;
        p0 += __shfl_xor(p0, 32);
        p1 += __shfl_xor(p1, 32);
        p2 += __shfl_xor(p2, 32);
        p3 += __shfl_xor(p3, 32);
    }
    if (!(tid & 32)) {                  // rg even: at is dead, alias as ta_s
        float4 t4; t4.x = p0; t4.y = p1; t4.z = p2; t4.w = p3;
        *(float4*)&ta_s[u * 128 + c0] = t4;
    }
    __syncthreads();

    // W_o + residual + LN2 (wave == node, pure shfl) + epilogue
    {
        int uu = tid >> 6, c = tid & 63;
        int n = n0 + uu;
        float o0 = b_o[c], o1 = b_o[c + 64];
        const float* tar = ta_s + uu * 128;
        #pragma unroll 8
        for (int k = 0; k < HID; k += 4) {
            float t0 = tar[k], t1 = tar[k+1], t2 = tar[k+2], t3 = tar[k+3];
            o0 += t0 * WoT[(size_t)(k+0)*128 + c]  + t1 * WoT[(size_t)(k+1)*128 + c]
                + t2 * WoT[(size_t)(k+2)*128 + c]  + t3 * WoT[(size_t)(k+3)*128 + c];
            o1 += t0 * WoT[(size_t)(k+0)*128 + c+64] + t1 * WoT[(size_t)(k+1)*128 + c+64]
                + t2 * WoT[(size_t)(k+2)*128 + c+64] + t3 * WoT[(size_t)(k+3)*128 + c+64];
        }
        float xa = xlast_g[(size_t)n * HID + c];
        float xb = xlast_g[(size_t)n * HID + c + 64];
        float x2a = xa + o0, x2b = xb + o1;
        float s = x2a + x2b, qs = x2a * x2a + x2b * x2b;
        #pragma unroll
        for (int m = 1; m < 64; m <<= 1) {
            s  += __shfl_xor(s, m);
            qs += __shfl_xor(qs, m);
        }
        float mu = s * (1.0f / HID);
        float var = qs * (1.0f / HID) - mu * mu;
        float rstd = rsqrtf(var + 1e-5f);
        float dv = sinf(((float)n / (float)N) * 6.28f) * 0.1f;
        out[(size_t)n * HID + c] =
            (x2a - mu) * rstd * g2[c] + be2[c] + dv
            + noise[(size_t)n * HID + c] * 0.05f;
        out[(size_t)n * HID + c + 64] =
            (x2b - mu) * rstd * g2[c + 64] + be2[c + 64] + dv
            + noise[(size_t)n * HID + c + 64] * 0.05f;
    }
}

// classifier: tiled h1 = emb@Wc1 + bc1 -> LN3 -> gelu -> logits
__global__ __launch_bounds__(256) void k_cls(const float* __restrict__ emb,
                                             const float* __restrict__ Wc1,
                                             const float* __restrict__ bc1,
                                             const float* __restrict__ gc,
                                             const float* __restrict__ bec,
                                             const float* __restrict__ Wc2,
                                             const float* __restrict__ bc2,
                                             float* __restrict__ out) {
    __shared__ float et[MT][HID];
    __shared__ float h1t[MT][HID + 1];
    int row0 = blockIdx.x * MT;
    int tid = threadIdx.x;

    for (int idx = tid; idx < MT * HID; idx += 256) {
        int r = idx >> 7, c = idx & 127;
        int row = row0 + r;
        et[r][c] = (row < N) ? emb[(size_t)row * HID + c] : 0.0f;
    }
    __syncthreads();

    {
        int cg = tid & 31, rg = tid >> 5;
        int c0 = cg * 4, r0 = rg * 4;
        float4 b4 = *(const float4*)(bc1 + c0);
        float a00=b4.x,a01=b4.y,a02=b4.z,a03=b4.w;
        float a10=b4.x,a11=b4.y,a12=b4.z,a13=b4.w;
        float a20=b4.x,a21=b4.y,a22=b4.z,a23=b4.w;
        float a30=b4.x,a31=b4.y,a32=b4.z,a33=b4.w;
        for (int k = 0; k < HID; ++k) {
            float4 w = *(const float4*)(Wc1 + (size_t)k * HID + c0);
            float e0 = et[r0 + 0][k], e1 = et[r0 + 1][k];
            float e2 = et[r0 + 2][k], e3 = et[r0 + 3][k];
            a00 += e0*w.x; a01 += e0*w.y; a02 += e0*w.z; a03 += e0*w.w;
            a10 += e1*w.x; a11 += e1*w.y; a12 += e1*w.z; a13 += e1*w.w;
            a20 += e2*w.x; a21 += e2*w.y; a22 += e2*w.z; a23 += e2*w.w;
            a30 += e3*w.x; a31 += e3*w.y; a32 += e3*w.z; a33 += e3*w.w;
        }
        h1t[r0+0][c0+0]=a00; h1t[r0+0][c0+1]=a01; h1t[r0+0][c0+2]=a02; h1t[r0+0][c0+3]=a03;
        h1t[r0+1][c0+0]=a10; h1t[r0+1][c0+1]=a11; h1t[r0+1][c0+2]=a12; h1t[r0+1][c0+3]=a13;
        h1t[r0+2][c0+0]=a20; h1t[r0+2][c0+1]=a21; h1t[r0+2][c0+2]=a22; h1t[r0+2][c0+3]=a23;
        h1t[r0+3][c0+0]=a30; h1t[r0+3][c0+1]=a31; h1t[r0+3][c0+2]=a32; h1t[r0+3][c0+3]=a33;
    }
    __syncthreads();

    // LN3 + gelu: 8 lanes per row (32 rows x 8 = 256 threads)
    {
        int r = tid >> 3, l = tid & 7;
        float p = 0.0f;
        #pragma unroll
        for (int k = 0; k < 16; ++k) p += h1t[r][l + 8 * k];
        #pragma unroll
        for (int m = 1; m < 8; m <<= 1) p += __shfl_xor(p, m);
        float mu = p * (1.0f / HID);
        float v = 0.0f;
        #pragma unroll
        for (int k = 0; k < 16; ++k) { float d = h1t[r][l + 8 * k] - mu; v += d * d; }
        #pragma unroll
        for (int m = 1; m < 8; m <<= 1) v += __shfl_xor(v, m);
        float rstd = rsqrtf(v * (1.0f / HID) + 1e-5f);
        #pragma unroll
        for (int k = 0; k < 16; ++k) {
            int c = l + 8 * k;
            float lnv = (h1t[r][c] - mu) * rstd * gc[c] + bec[c];
            h1t[r][c] = 0.5f * lnv * (1.0f + erff(lnv * 0.70710678118f));
        }
    }
    __syncthreads();

    // logits: 64 outputs (32 rows x 2)
    if (tid < MT * NC) {
        int r = tid >> 1, j = tid & 1;
        int row = row0 + r;
        if (row < N) {
            float acc = bc2[j];
            #pragma unroll 8
            for (int c = 0; c < HID; ++c) acc += h1t[r][c] * Wc2[c * NC + j];
            if (j == 1) acc += sinf((float)row * 0.5f) * 0.2f;
            out[(size_t)N * HID + (size_t)row * NC + j] = acc;
        }
    }
}

extern "C" void kernel_launch(void* const* d_in, const int* in_sizes, int n_in,
                              void* d_out, int out_size, void* d_ws, size_t ws_size,
                              hipStream_t stream) {
    const float* x      = (const float*)d_in[0];
    const int*   ei     = (const int*)d_in[1];
    const float* noise  = (const float*)d_in[2];
    const float* W_proj = (const float*)d_in[3];
    const float* b_proj = (const float*)d_in[4];
    const float* W_gat  = (const float*)d_in[5];
    const float* a_src  = (const float*)d_in[6];
    const float* a_dst  = (const float*)d_in[7];
    const float* b_gat  = (const float*)d_in[8];
    const float* g1     = (const float*)d_in[9];
    const float* be1    = (const float*)d_in[10];
    const float* W_qkv  = (const float*)d_in[11];
    const float* b_qkv  = (const float*)d_in[12];
    const float* W_o    = (const float*)d_in[13];
    const float* b_o    = (const float*)d_in[14];
    const float* g2     = (const float*)d_in[15];
    const float* be2    = (const float*)d_in[16];
    const float* Wc1    = (const float*)d_in[17];
    const float* bc1    = (const float*)d_in[18];
    const float* gc     = (const float*)d_in[19];
    const float* bec    = (const float*)d_in[20];
    const float* Wc2    = (const float*)d_in[21];
    const float* bc2    = (const float*)d_in[22];
    float* out = (float*)d_out;

    float* xh     = (float*)d_ws;                  //  5,120,000
    float* nrm    = xh + 5120000;                  //  5,120,000 (node-major)
    float* a_s    = nrm + 5120000;                 //    320,000
    float* a_d    = a_s + 320000;                  //    320,000
    int*   offs    = (int*)(a_d + 320000);         //     40,008
    int*   cursor  = offs + 40008;                 //     40,000
    unsigned short* csr_src = (unsigned short*)(cursor + 40000); // 1,320,000 u16
    float* WTq    = (float*)(cursor + 40000 + 1320000);  //  49,152 (past csr int-region)
    float* WoT    = WTq + 49152;                   //     16,384
    float* xlastg = WoT + 16384;                   //    640,000

    hipMemsetAsync(cursor, 0, 40000 * sizeof(int), stream);

    k_front<<<NB_HIST + NB_TR + NB_PG, 256, 0, stream>>>(
        x, W_proj, b_proj, W_gat, a_src, a_dst, xh, a_s, a_d,
        W_qkv, W_o, WTq, WoT, ei, cursor);

    k_scan<<<T, 256, 0, stream>>>(cursor, offs);
    k_scatter<<<64 * NCHK, 256, 0, stream>>>(ei, cursor, csr_src);

    k_aggc<<<T * N, 128, 0, stream>>>(offs, csr_src, a_s, a_d, xh,
                                      b_gat, g1, be1, nrm, xlastg);

    k_fuse<<<N / NBF, 256, 0, stream>>>(nrm, WTq, b_qkv, xlastg, WoT, b_o,
                                        g2, be2, noise, out);

    k_cls<<<(N + MT - 1) / MT, 256, 0, stream>>>(out, Wc1, bc1, gc, bec, Wc2, bc2, out);
}

// Round 17
// 340.714 us; speedup vs baseline: 1.0160x; 1.0160x over previous
//
#include <hip/hip_runtime.h>
#include <math.h>

#define T 8
#define N 5000
#define E 160000
#define EN (E + N)
#define IN_DIM 64
#define HID 128
#define H 8
#define D 16
#define NC 2
#define MT 32            // rows per tiled-GEMM block
#define NBF 4            // nodes per k_fuse block
#define NRR 8            // dst ranges for k_scatter
#define NCHK 32          // edge chunks per t for k_scatter
#define NHCH 32          // edge chunks per t for k_hist
#define RSZ ((N + NRR - 1) / NRR)      // 625
#define CSZ ((EN + NCHK - 1) / NCHK)   // 5157

#define NB_HIST (T * NHCH)             // 256 hist-role blocks
#define NB_TR   256                    // transpose-role blocks
#define NB_PG   (T * N / MT)           // 1250 GEMM-role blocks

__device__ __forceinline__ float leaky(float e) { return (e >= 0.0f) ? e : 0.2f * e; }

// k_front: three independent roles fused into one dispatch so they overlap:
//   blocks [0, NB_HIST)            : LDS-privatized degree histogram
//   blocks [NB_HIST, +NB_TR)       : W_qkv / W_o transposes
//   blocks [NB_HIST+NB_TR, +NB_PG) : fused h=relu(x@Wp+bp); xh=h@Wg; a_s/a_d
// cursor must be zeroed by hipMemsetAsync BEFORE this kernel.
__global__ __launch_bounds__(256) void k_front(
        // pg role
        const float* __restrict__ x,
        const float* __restrict__ Wp,
        const float* __restrict__ bp,
        const float* __restrict__ Wg,
        const float* __restrict__ asrc,
        const float* __restrict__ adst,
        float* __restrict__ xh,
        float* __restrict__ a_s,
        float* __restrict__ a_d,
        // tr role
        const float* __restrict__ W_qkv,
        const float* __restrict__ W_o,
        float* __restrict__ WTq,
        float* __restrict__ WoT,
        // hist role
        const int* __restrict__ ei,
        int* __restrict__ cursor) {
    __shared__ float smem[6272];      // 25,088 B: pg 24,704 / hist 20,000
    int bid = blockIdx.x;
    int tid = threadIdx.x;

    if (bid < NB_HIST) {
        // ---------------- histogram role ----------------
        int* hist = (int*)smem;       // N ints = 20,000 B
        int t = bid >> 5;
        int chunk = bid & 31;

        for (int i = tid; i < N; i += 256) hist[i] = 0;
        __syncthreads();

        const int CS = (EN + NHCH - 1) / NHCH;   // 5157
        int i0 = chunk * CS;
        int i1 = (i0 + CS < EN) ? i0 + CS : EN;
        const int* drow = ei + (size_t)(2 * t + 1) * E;
        for (int i = i0 + tid; i < i1; i += 256) {
            int d = (i < E) ? drow[i] : (i - E);
            atomicAdd(&hist[d], 1);
        }
        __syncthreads();

        int* cur = cursor + t * N;
        for (int i = tid; i < N; i += 256) {
            int c = hist[i];
            if (c) atomicAdd(&cur[i], c);
        }
        return;
    }

    if (bid < NB_HIST + NB_TR) {
        // ---------------- transpose role ----------------
        int idx = (bid - NB_HIST) * 256 + tid;
        if (idx < 384 * 128) {
            int j = idx >> 7, c = idx & 127;
            WTq[c * 384 + j] = W_qkv[idx];
        } else if (idx < 384 * 128 + 128 * 128) {
            int r = idx - 384 * 128;
            int j = r >> 7, k = r & 127;
            WoT[k * 128 + j] = W_o[r];
        }
        return;
    }

    // ---------------- pg (GEMM) role ----------------
    float (*xt)[IN_DIM] = (float (*)[IN_DIM])smem;
    float (*ht)[HID + 1] = (float (*)[HID + 1])(smem + MT * IN_DIM);
    int row0 = (bid - NB_HIST - NB_TR) * MT;

    for (int idx = tid; idx < MT * IN_DIM; idx += 256) {
        int r = idx >> 6, k = idx & 63;
        xt[r][k] = x[(size_t)(row0 + r) * IN_DIM + k];
    }
    __syncthreads();

    int cg = tid & 31;
    int rg = tid >> 5;
    int c0 = cg * 4, r0 = rg * 4;

    {
        float4 b4 = *(const float4*)(bp + c0);
        float a00=b4.x,a01=b4.y,a02=b4.z,a03=b4.w;
        float a10=b4.x,a11=b4.y,a12=b4.z,a13=b4.w;
        float a20=b4.x,a21=b4.y,a22=b4.z,a23=b4.w;
        float a30=b4.x,a31=b4.y,a32=b4.z,a33=b4.w;
        for (int k = 0; k < IN_DIM; ++k) {
            float4 w = *(const float4*)(Wp + (size_t)k * HID + c0);
            float x0 = xt[r0 + 0][k], x1 = xt[r0 + 1][k];
            float x2 = xt[r0 + 2][k], x3 = xt[r0 + 3][k];
            a00 += x0*w.x; a01 += x0*w.y; a02 += x0*w.z; a03 += x0*w.w;
            a10 += x1*w.x; a11 += x1*w.y; a12 += x1*w.z; a13 += x1*w.w;
            a20 += x2*w.x; a21 += x2*w.y; a22 += x2*w.z; a23 += x2*w.w;
            a30 += x3*w.x; a31 += x3*w.y; a32 += x3*w.z; a33 += x3*w.w;
        }
        ht[r0+0][c0+0]=fmaxf(a00,0.f); ht[r0+0][c0+1]=fmaxf(a01,0.f);
        ht[r0+0][c0+2]=fmaxf(a02,0.f); ht[r0+0][c0+3]=fmaxf(a03,0.f);
        ht[r0+1][c0+0]=fmaxf(a10,0.f); ht[r0+1][c0+1]=fmaxf(a11,0.f);
        ht[r0+1][c0+2]=fmaxf(a12,0.f); ht[r0+1][c0+3]=fmaxf(a13,0.f);
        ht[r0+2][c0+0]=fmaxf(a20,0.f); ht[r0+2][c0+1]=fmaxf(a21,0.f);
        ht[r0+2][c0+2]=fmaxf(a22,0.f); ht[r0+2][c0+3]=fmaxf(a23,0.f);
        ht[r0+3][c0+0]=fmaxf(a30,0.f); ht[r0+3][c0+1]=fmaxf(a31,0.f);
        ht[r0+3][c0+2]=fmaxf(a32,0.f); ht[r0+3][c0+3]=fmaxf(a33,0.f);
    }
    __syncthreads();

    float a00=0,a01=0,a02=0,a03=0, a10=0,a11=0,a12=0,a13=0;
    float a20=0,a21=0,a22=0,a23=0, a30=0,a31=0,a32=0,a33=0;
    for (int k = 0; k < HID; ++k) {
        float4 w = *(const float4*)(Wg + (size_t)k * HID + c0);
        float h0 = ht[r0 + 0][k], h1 = ht[r0 + 1][k];
        float h2 = ht[r0 + 2][k], h3 = ht[r0 + 3][k];
        a00 += h0*w.x; a01 += h0*w.y; a02 += h0*w.z; a03 += h0*w.w;
        a10 += h1*w.x; a11 += h1*w.y; a12 += h1*w.z; a13 += h1*w.w;
        a20 += h2*w.x; a21 += h2*w.y; a22 += h2*w.z; a23 += h2*w.w;
        a30 += h3*w.x; a31 += h3*w.y; a32 += h3*w.z; a33 += h3*w.w;
    }
    {
        float4 v;
        v.x=a00; v.y=a01; v.z=a02; v.w=a03;
        *(float4*)(xh + (size_t)(row0 + r0 + 0) * HID + c0) = v;
        v.x=a10; v.y=a11; v.z=a12; v.w=a13;
        *(float4*)(xh + (size_t)(row0 + r0 + 1) * HID + c0) = v;
        v.x=a20; v.y=a21; v.z=a22; v.w=a23;
        *(float4*)(xh + (size_t)(row0 + r0 + 2) * HID + c0) = v;
        v.x=a30; v.y=a31; v.z=a32; v.w=a33;
        *(float4*)(xh + (size_t)(row0 + r0 + 3) * HID + c0) = v;
    }
    __syncthreads();
    ht[r0+0][c0+0]=a00; ht[r0+0][c0+1]=a01; ht[r0+0][c0+2]=a02; ht[r0+0][c0+3]=a03;
    ht[r0+1][c0+0]=a10; ht[r0+1][c0+1]=a11; ht[r0+1][c0+2]=a12; ht[r0+1][c0+3]=a13;
    ht[r0+2][c0+0]=a20; ht[r0+2][c0+1]=a21; ht[r0+2][c0+2]=a22; ht[r0+2][c0+3]=a23;
    ht[r0+3][c0+0]=a30; ht[r0+3][c0+1]=a31; ht[r0+3][c0+2]=a32; ht[r0+3][c0+3]=a33;
    __syncthreads();

    {
        int r = tid >> 3, hh = tid & 7;
        float s1 = 0.0f, s2 = 0.0f;
        #pragma unroll
        for (int d = 0; d < D; ++d) {
            float v = ht[r][hh * D + d];
            s1 += v * asrc[hh * D + d];
            s2 += v * adst[hh * D + d];
        }
        a_s[(size_t)(row0 + r) * H + hh] = s1;
        a_d[(size_t)(row0 + r) * H + hh] = s2;
    }
}

__global__ void k_scan(int* __restrict__ cursor, int* __restrict__ offs) {
    __shared__ int part[256];
    int t = blockIdx.x;
    int tid = threadIdx.x;
    const int CH = 20;
    int begin = tid * CH;
    int sum = 0;
    for (int k = 0; k < CH; ++k) {
        int i = begin + k;
        if (i < N) sum += cursor[t * N + i];
    }
    part[tid] = sum;
    __syncthreads();
    if (tid == 0) {
        int run = 0;
        for (int i = 0; i < 256; ++i) { int v = part[i]; part[i] = run; run += v; }
        offs[t * (N + 1) + N] = run;
    }
    __syncthreads();
    int run = part[tid];
    for (int k = 0; k < CH; ++k) {
        int i = begin + k;
        if (i < N) {
            int cnt = cursor[t * N + i];
            offs[t * (N + 1) + i] = run;
            cursor[t * N + i] = run;
            run += cnt;
        }
    }
}

// range-localized scatter: block = (t, dst-range r, edge-chunk c). All CSR
// writes of a block land in one contiguous ~82KB region; index swizzle pins
// each (t,r)'s chunks to one XCD so dirty lines fill before writeback.
__global__ __launch_bounds__(256) void k_scatter(const int* __restrict__ ei,
                                                 int* __restrict__ cursor,
                                                 int* __restrict__ csr_src) {
    int idx = blockIdx.x;
    int g = idx & 63;            // (t, r)
    int c = idx >> 6;            // chunk
    int t = g >> 3;
    int r = g & 7;
    int lo = r * RSZ;
    int hi = (lo + RSZ < N) ? lo + RSZ : N;
    int i0 = c * CSZ;
    int i1 = (i0 + CSZ < EN) ? i0 + CSZ : EN;

    const int* srow = ei + (size_t)(2 * t) * E;
    const int* drow = srow + E;
    int* cur = cursor + t * N;
    int* csb = csr_src + (size_t)t * EN;

    for (int i = i0 + threadIdx.x; i < i1; i += 256) {
        int s, d;
        if (i < E) { d = drow[i]; s = srow[i]; }
        else       { s = d = i - E; }
        if (d >= lo && d < hi) {
            int pos = atomicAdd(&cur[d], 1);
            csb[pos] = s;
        }
    }
}

// GAT aggregation + fused LN1, one block per (dst,t), atomic-free and
// BARRIER-FREE inner loop. Single-pass softmax. Node-major nrm.
__global__ __launch_bounds__(128) void k_aggc(
        const int* __restrict__ offs, const int* __restrict__ csr_src,
        const float* __restrict__ a_s, const float* __restrict__ a_d,
        const float* __restrict__ xh, const float* __restrict__ b_gat,
        const float* __restrict__ g1, const float* __restrict__ be1,
        float* __restrict__ nrm, float* __restrict__ xlast_g) {
    int b = blockIdx.x;
    int t = b & 7;            // T == 8
    int dst = b >> 3;
    int tid = threadIdx.x;

    int o0 = offs[t * (N + 1) + dst];
    int o1 = offs[t * (N + 1) + dst + 1];
    int deg = o1 - o0;
    const int* esrc = csr_src + (size_t)t * EN + o0;
    const float* as_b = a_s + (size_t)t * N * H;
    const float* ad_b = a_d + (size_t)t * N * H;
    const float* xh_b = xh + (size_t)t * N * HID;

    __shared__ float ws_s[2][H];     // per-wave wsum partials
    __shared__ float pacc[2][HID];   // per-wave acc partials
    __shared__ float red[128];

    int el = tid >> 5;               // edge-lane: edges ej % 4 == el
    int cg = tid & 31;               // col group (cols 4cg..4cg+3)
    int hg = cg >> 2;                // head of these cols
    float adh = ad_b[dst * H + hg];

    float4 acc = {0.0f, 0.0f, 0.0f, 0.0f};
    float wpart = 0.0f;

    #pragma unroll 4
    for (int ej = el; ej < deg; ej += 4) {
        int src = esrc[ej];
        float w = expf(leaky(as_b[src * H + hg] + adh));
        wpart += w;
        float4 v = *(const float4*)(xh_b + (size_t)src * HID + (cg << 2));
        acc.x += w * v.x; acc.y += w * v.y;
        acc.z += w * v.z; acc.w += w * v.w;
    }

    wpart += __shfl_xor(wpart, 32);
    acc.x += __shfl_xor(acc.x, 32);
    acc.y += __shfl_xor(acc.y, 32);
    acc.z += __shfl_xor(acc.z, 32);
    acc.w += __shfl_xor(acc.w, 32);
    if (!(tid & 32)) {
        if ((cg & 3) == 0) ws_s[tid >> 6][hg] = wpart;
        *(float4*)&pacc[tid >> 6][cg << 2] = acc;
    }
    __syncthreads();

    float wsum = ws_s[0][tid >> 4] + ws_s[1][tid >> 4];
    float val = (pacc[0][tid] + pacc[1][tid]) / (wsum + 1e-16f);

    // ---- fused LN1 over this (t,dst) row ----
    float v = val + b_gat[tid];
    red[tid] = v;
    __syncthreads();
    if (tid < 64) {
        float s = red[tid] + red[tid + 64];
        #pragma unroll
        for (int m = 1; m < 64; m <<= 1) s += __shfl_xor(s, m);
        if (tid == 0) red[0] = s;
    }
    __syncthreads();
    float mu = red[0] * (1.0f / HID);
    __syncthreads();
    float dv = v - mu;
    red[tid] = dv * dv;
    __syncthreads();
    if (tid < 64) {
        float s = red[tid] + red[tid + 64];
        #pragma unroll
        for (int m = 1; m < 64; m <<= 1) s += __shfl_xor(s, m);
        if (tid == 0) red[0] = s;
    }
    __syncthreads();
    float rstd = rsqrtf(red[0] * (1.0f / HID) + 1e-5f);

    nrm[(size_t)(dst * T + t) * HID + tid] = dv * rstd * g1[tid] + be1[tid];
    if (t == T - 1) xlast_g[(size_t)dst * HID + tid] = v;
}

// fused qkv GEMM + attention + W_o + LN2 + epilogue for NBF=4 nodes/block.
// Weight chunks staged via async global_load_lds into a DOUBLE-BUFFERED ws.
__global__ __launch_bounds__(256) void k_fuse(
        const float* __restrict__ nrm,      // [N*T][HID] node-major
        const float* __restrict__ WTq,      // [128][384]
        const float* __restrict__ b_qkv,
        const float* __restrict__ xlast_g,
        const float* __restrict__ WoT,
        const float* __restrict__ b_o,
        const float* __restrict__ g2, const float* __restrict__ be2,
        const float* __restrict__ noise, float* __restrict__ out) {
    __shared__ float at[NBF * T][HID];       // 16 KB; ta_s aliases after GEMM
    __shared__ float ql[NBF][HID];           // 2 KB
    __shared__ float ws[2][8][384];          // 24 KB double-buffered stage
    float* ta_s = &at[0][0];                 // [NBF][HID] = 512 floats (alias)

    int n0 = blockIdx.x * NBF;
    int tid = threadIdx.x;
    int cg = tid & 31, rg = tid >> 5;
    int c0 = cg * 4, r0 = rg * 4;
    int u = rg >> 1;                         // node of this thread's 4 rows
    int lane = tid & 63, wv = tid >> 6;

    auto stage = [&](int kc, int buf) {
        const float* g = WTq + (size_t)kc * 3072 + wv * 768 + (lane << 2);
        float* l = &ws[buf][0][0] + wv * 768;
        #pragma unroll
        for (int j = 0; j < 3; ++j) {
            __builtin_amdgcn_global_load_lds(
                (const __attribute__((address_space(1))) void*)(g + j * 256),
                (__attribute__((address_space(3))) void*)(l + j * 256),
                16, 0, 0);
        }
    };

    // load 32 rows of nrm (coalesced float4)
    {
        const float* srcp = nrm + (size_t)n0 * T * HID;
        for (int idx = tid; idx < NBF * T * 32; idx += 256) {
            int r = idx >> 5, c4 = (idx & 31) << 2;
            *(float4*)&at[r][c4] = *(const float4*)(srcp + (size_t)r * HID + c4);
        }
    }
    stage(0, 0);                             // prologue: chunk 0 in flight

    // accumulators (bias-initialized)
    float ka[4][4], va[4][4], qa[4];
    {
        float4 bk = *(const float4*)(b_qkv + 128 + c0);
        float4 bv = *(const float4*)(b_qkv + 256 + c0);
        #pragma unroll
        for (int i = 0; i < 4; ++i) {
            ka[i][0] = bk.x; ka[i][1] = bk.y; ka[i][2] = bk.z; ka[i][3] = bk.w;
            va[i][0] = bv.x; va[i][1] = bv.y; va[i][2] = bv.z; va[i][3] = bv.w;
        }
        if (rg < 4) {
            float4 bq = *(const float4*)(b_qkv + c0);
            qa[0] = bq.x; qa[1] = bq.y; qa[2] = bq.z; qa[3] = bq.w;
        } else {
            qa[0] = qa[1] = qa[2] = qa[3] = 0.0f;
        }
    }
    __syncthreads();                         // at ready + ws[0] drained

    const float* atq = at[(rg & 3) * T + (T - 1)];  // q source row (waves 0-1)

    int cur = 0;
    for (int kc = 0; kc < 16; ++kc) {
        if (kc < 15) stage(kc + 1, cur ^ 1); // async, hidden under compute

        #pragma unroll
        for (int kk = 0; kk < 8; kk += 4) {
            int k = kc * 8 + kk;
            float4 e0 = *(const float4*)&at[r0 + 0][k];
            float4 e1 = *(const float4*)&at[r0 + 1][k];
            float4 e2 = *(const float4*)&at[r0 + 2][k];
            float4 e3 = *(const float4*)&at[r0 + 3][k];
            float e0a[4] = {e0.x, e0.y, e0.z, e0.w};
            float e1a[4] = {e1.x, e1.y, e1.z, e1.w};
            float e2a[4] = {e2.x, e2.y, e2.z, e2.w};
            float e3a[4] = {e3.x, e3.y, e3.z, e3.w};
            float eqa[4] = {0.f, 0.f, 0.f, 0.f};
            if (rg < 4) {
                float4 eq = *(const float4*)&atq[k];
                eqa[0] = eq.x; eqa[1] = eq.y; eqa[2] = eq.z; eqa[3] = eq.w;
            }
            #pragma unroll
            for (int j = 0; j < 4; ++j) {
                float4 wk = *(const float4*)&ws[cur][kk + j][128 + c0];
                float4 wv4 = *(const float4*)&ws[cur][kk + j][256 + c0];
                float x0 = e0a[j], x1 = e1a[j], x2 = e2a[j], x3 = e3a[j];
                ka[0][0] += x0*wk.x; ka[0][1] += x0*wk.y; ka[0][2] += x0*wk.z; ka[0][3] += x0*wk.w;
                ka[1][0] += x1*wk.x; ka[1][1] += x1*wk.y; ka[1][2] += x1*wk.z; ka[1][3] += x1*wk.w;
                ka[2][0] += x2*wk.x; ka[2][1] += x2*wk.y; ka[2][2] += x2*wk.z; ka[2][3] += x2*wk.w;
                ka[3][0] += x3*wk.x; ka[3][1] += x3*wk.y; ka[3][2] += x3*wk.z; ka[3][3] += x3*wk.w;
                va[0][0] += x0*wv4.x; va[0][1] += x0*wv4.y; va[0][2] += x0*wv4.z; va[0][3] += x0*wv4.w;
                va[1][0] += x1*wv4.x; va[1][1] += x1*wv4.y; va[1][2] += x1*wv4.z; va[1][3] += x1*wv4.w;
                va[2][0] += x2*wv4.x; va[2][1] += x2*wv4.y; va[2][2] += x2*wv4.z; va[2][3] += x2*wv4.w;
                va[3][0] += x3*wv4.x; va[3][1] += x3*wv4.y; va[3][2] += x3*wv4.z; va[3][3] += x3*wv4.w;
                if (rg < 4) {
                    float4 wq = *(const float4*)&ws[cur][kk + j][c0];
                    float xq = eqa[j];
                    qa[0] += xq*wq.x; qa[1] += xq*wq.y; qa[2] += xq*wq.z; qa[3] += xq*wq.w;
                }
            }
        }
        __syncthreads();   // retires ws[cur] reads + drains kc+1's async loads
        cur ^= 1;
    }

    // q to LDS (waves 0-1)
    if (rg < 4) {
        float4 q4; q4.x = qa[0]; q4.y = qa[1]; q4.z = qa[2]; q4.w = qa[3];
        *(float4*)&ql[rg][c0] = q4;
    }
    __syncthreads();

    // scores in registers; quad shfl completes dot; partner shfl(32) for
    // softmax + PV.
    float p0, p1, p2, p3;
    {
        float4 q4 = *(const float4*)&ql[u][c0];
        float ps[4];
        #pragma unroll
        for (int i = 0; i < 4; ++i) {
            float s = q4.x * ka[i][0] + q4.y * ka[i][1]
                    + q4.z * ka[i][2] + q4.w * ka[i][3];
            s += __shfl_xor(s, 1);
            s += __shfl_xor(s, 2);
            ps[i] = s * 0.25f;          // 1/sqrt(D)
        }
        float mx = fmaxf(fmaxf(ps[0], ps[1]), fmaxf(ps[2], ps[3]));
        mx = fmaxf(mx, __shfl_xor(mx, 32));
        float e0 = expf(ps[0] - mx), e1 = expf(ps[1] - mx);
        float e2 = expf(ps[2] - mx), e3 = expf(ps[3] - mx);
        float ssum = e0 + e1 + e2 + e3;
        ssum += __shfl_xor(ssum, 32);
        float inv = 1.0f / ssum;
        p0 = (e0 * va[0][0] + e1 * va[1][0] + e2 * va[2][0] + e3 * va[3][0]) * inv;
        p1 = (e0 * va[0][1] + e1 * va[1][1] + e2 * va[2][1] + e3 * va[3][1]) * inv;
        p2 = (e0 * va[0][2] + e1 * va[1][2] + e2 * va[2][2] + e3 * va[3][2]) * inv;
        p3 = (e0 * va[0][3] + e1 * va[1][3] + e2 * va[2][3] + e3 * va[3][3]) * inv;
        p0 += __shfl_xor(p0, 32);
        p1 += __shfl_xor(p1, 32);
        p2 += __shfl_xor(p2, 32);
        p3 += __shfl_xor(p3, 32);
    }
    if (!(tid & 32)) {                  // rg even: at is dead, alias as ta_s
        float4 t4; t4.x = p0; t4.y = p1; t4.z = p2; t4.w = p3;
        *(float4*)&ta_s[u * 128 + c0] = t4;
    }
    __syncthreads();

    // W_o + residual + LN2 (wave == node, pure shfl) + epilogue
    {
        int uu = tid >> 6, c = tid & 63;
        int n = n0 + uu;
        float o0 = b_o[c], o1 = b_o[c + 64];
        const float* tar = ta_s + uu * 128;
        #pragma unroll 8
        for (int k = 0; k < HID; k += 4) {
            float t0 = tar[k], t1 = tar[k+1], t2 = tar[k+2], t3 = tar[k+3];
            o0 += t0 * WoT[(size_t)(k+0)*128 + c]  + t1 * WoT[(size_t)(k+1)*128 + c]
                + t2 * WoT[(size_t)(k+2)*128 + c]  + t3 * WoT[(size_t)(k+3)*128 + c];
            o1 += t0 * WoT[(size_t)(k+0)*128 + c+64] + t1 * WoT[(size_t)(k+1)*128 + c+64]
                + t2 * WoT[(size_t)(k+2)*128 + c+64] + t3 * WoT[(size_t)(k+3)*128 + c+64];
        }
        float xa = xlast_g[(size_t)n * HID + c];
        float xb = xlast_g[(size_t)n * HID + c + 64];
        float x2a = xa + o0, x2b = xb + o1;
        float s = x2a + x2b, qs = x2a * x2a + x2b * x2b;
        #pragma unroll
        for (int m = 1; m < 64; m <<= 1) {
            s  += __shfl_xor(s, m);
            qs += __shfl_xor(qs, m);
        }
        float mu = s * (1.0f / HID);
        float var = qs * (1.0f / HID) - mu * mu;
        float rstd = rsqrtf(var + 1e-5f);
        float dv = sinf(((float)n / (float)N) * 6.28f) * 0.1f;
        out[(size_t)n * HID + c] =
            (x2a - mu) * rstd * g2[c] + be2[c] + dv
            + noise[(size_t)n * HID + c] * 0.05f;
        out[(size_t)n * HID + c + 64] =
            (x2b - mu) * rstd * g2[c + 64] + be2[c + 64] + dv
            + noise[(size_t)n * HID + c + 64] * 0.05f;
    }
}

// classifier: tiled h1 = emb@Wc1 + bc1 -> LN3 -> gelu -> logits
__global__ __launch_bounds__(256) void k_cls(const float* __restrict__ emb,
                                             const float* __restrict__ Wc1,
                                             const float* __restrict__ bc1,
                                             const float* __restrict__ gc,
                                             const float* __restrict__ bec,
                                             const float* __restrict__ Wc2,
                                             const float* __restrict__ bc2,
                                             float* __restrict__ out) {
    __shared__ float et[MT][HID];
    __shared__ float h1t[MT][HID + 1];
    int row0 = blockIdx.x * MT;
    int tid = threadIdx.x;

    for (int idx = tid; idx < MT * HID; idx += 256) {
        int r = idx >> 7, c = idx & 127;
        int row = row0 + r;
        et[r][c] = (row < N) ? emb[(size_t)row * HID + c] : 0.0f;
    }
    __syncthreads();

    {
        int cg = tid & 31, rg = tid >> 5;
        int c0 = cg * 4, r0 = rg * 4;
        float4 b4 = *(const float4*)(bc1 + c0);
        float a00=b4.x,a01=b4.y,a02=b4.z,a03=b4.w;
        float a10=b4.x,a11=b4.y,a12=b4.z,a13=b4.w;
        float a20=b4.x,a21=b4.y,a22=b4.z,a23=b4.w;
        float a30=b4.x,a31=b4.y,a32=b4.z,a33=b4.w;
        for (int k = 0; k < HID; ++k) {
            float4 w = *(const float4*)(Wc1 + (size_t)k * HID + c0);
            float e0 = et[r0 + 0][k], e1 = et[r0 + 1][k];
            float e2 = et[r0 + 2][k], e3 = et[r0 + 3][k];
            a00 += e0*w.x; a01 += e0*w.y; a02 += e0*w.z; a03 += e0*w.w;
            a10 += e1*w.x; a11 += e1*w.y; a12 += e1*w.z; a13 += e1*w.w;
            a20 += e2*w.x; a21 += e2*w.y; a22 += e2*w.z; a23 += e2*w.w;
            a30 += e3*w.x; a31 += e3*w.y; a32 += e3*w.z; a33 += e3*w.w;
        }
        h1t[r0+0][c0+0]=a00; h1t[r0+0][c0+1]=a01; h1t[r0+0][c0+2]=a02; h1t[r0+0][c0+3]=a03;
        h1t[r0+1][c0+0]=a10; h1t[r0+1][c0+1]=a11; h1t[r0+1][c0+2]=a12; h1t[r0+1][c0+3]=a13;
        h1t[r0+2][c0+0]=a20; h1t[r0+2][c0+1]=a21; h1t[r0+2][c0+2]=a22; h1t[r0+2][c0+3]=a23;
        h1t[r0+3][c0+0]=a30; h1t[r0+3][c0+1]=a31; h1t[r0+3][c0+2]=a32; h1t[r0+3][c0+3]=a33;
    }
    __syncthreads();

    // LN3 + gelu: 8 lanes per row (32 rows x 8 = 256 threads)
    {
        int r = tid >> 3, l = tid & 7;
        float p = 0.0f;
        #pragma unroll
        for (int k = 0; k < 16; ++k) p += h1t[r][l + 8 * k];
        #pragma unroll
        for (int m = 1; m < 8; m <<= 1) p += __shfl_xor(p, m);
        float mu = p * (1.0f / HID);
        float v = 0.0f;
        #pragma unroll
        for (int k = 0; k < 16; ++k) { float d = h1t[r][l + 8 * k] - mu; v += d * d; }
        #pragma unroll
        for (int m = 1; m < 8; m <<= 1) v += __shfl_xor(v, m);
        float rstd = rsqrtf(v * (1.0f / HID) + 1e-5f);
        #pragma unroll
        for (int k = 0; k < 16; ++k) {
            int c = l + 8 * k;
            float lnv = (h1t[r][c] - mu) * rstd * gc[c] + bec[c];
            h1t[r][c] = 0.5f * lnv * (1.0f + erff(lnv * 0.70710678118f));
        }
    }
    __syncthreads();

    // logits: 64 outputs (32 rows x 2)
    if (tid < MT * NC) {
        int r = tid >> 1, j = tid & 1;
        int row = row0 + r;
        if (row < N) {
            float acc = bc2[j];
            #pragma unroll 8
            for (int c = 0; c < HID; ++c) acc += h1t[r][c] * Wc2[c * NC + j];
            if (j == 1) acc += sinf((float)row * 0.5f) * 0.2f;
            out[(size_t)N * HID + (size_t)row * NC + j] = acc;
        }
    }
}

extern "C" void kernel_launch(void* const* d_in, const int* in_sizes, int n_in,
                              void* d_out, int out_size, void* d_ws, size_t ws_size,
                              hipStream_t stream) {
    const float* x      = (const float*)d_in[0];
    const int*   ei     = (const int*)d_in[1];
    const float* noise  = (const float*)d_in[2];
    const float* W_proj = (const float*)d_in[3];
    const float* b_proj = (const float*)d_in[4];
    const float* W_gat  = (const float*)d_in[5];
    const float* a_src  = (const float*)d_in[6];
    const float* a_dst  = (const float*)d_in[7];
    const float* b_gat  = (const float*)d_in[8];
    const float* g1     = (const float*)d_in[9];
    const float* be1    = (const float*)d_in[10];
    const float* W_qkv  = (const float*)d_in[11];
    const float* b_qkv  = (const float*)d_in[12];
    const float* W_o    = (const float*)d_in[13];
    const float* b_o    = (const float*)d_in[14];
    const float* g2     = (const float*)d_in[15];
    const float* be2    = (const float*)d_in[16];
    const float* Wc1    = (const float*)d_in[17];
    const float* bc1    = (const float*)d_in[18];
    const float* gc     = (const float*)d_in[19];
    const float* bec    = (const float*)d_in[20];
    const float* Wc2    = (const float*)d_in[21];
    const float* bc2    = (const float*)d_in[22];
    float* out = (float*)d_out;

    float* xh     = (float*)d_ws;                  //  5,120,000
    float* nrm    = xh + 5120000;                  //  5,120,000 (node-major)
    float* a_s    = nrm + 5120000;                 //    320,000
    float* a_d    = a_s + 320000;                  //    320,000
    int*   offs    = (int*)(a_d + 320000);         //     40,008
    int*   cursor  = offs + 40008;                 //     40,000
    int*   csr_src = cursor + 40000;               //  1,320,000
    float* WTq    = (float*)(csr_src + 1320000);   //     49,152
    float* WoT    = WTq + 49152;                   //     16,384
    float* xlastg = WoT + 16384;                   //    640,000

    hipMemsetAsync(cursor, 0, 40000 * sizeof(int), stream);

    k_front<<<NB_HIST + NB_TR + NB_PG, 256, 0, stream>>>(
        x, W_proj, b_proj, W_gat, a_src, a_dst, xh, a_s, a_d,
        W_qkv, W_o, WTq, WoT, ei, cursor);

    k_scan<<<T, 256, 0, stream>>>(cursor, offs);
    k_scatter<<<64 * NCHK, 256, 0, stream>>>(ei, cursor, csr_src);

    k_aggc<<<T * N, 128, 0, stream>>>(offs, csr_src, a_s, a_d, xh,
                                      b_gat, g1, be1, nrm, xlastg);

    k_fuse<<<N / NBF, 256, 0, stream>>>(nrm, WTq, b_qkv, xlastg, WoT, b_o,
                                        g2, be2, noise, out);

    k_cls<<<(N + MT - 1) / MT, 256, 0, stream>>>(out, Wc1, bc1, gc, bec, Wc2, bc2, out);
}